// Round 1
// baseline (247.805 us; speedup 1.0000x reference)
//
#include <hip/hip_runtime.h>

// ROI pooling / crop-and-resize, bilinear, half-pixel centers.
// fm: (64,64,128) fp32 NHWC; rois: (N,4) int32 [x1,y1,x2,y2]; out: (N,7,7,128) fp32.
// Write-bound: 250.9 MB output. One block per ROI; 32 lanes x float4 = 128 ch
// per (py,px) position -> 512B coalesced stores; 8 positions/iter, 7 iters.

#define POOL 7
#define CH   128
#define FH   64
#define FW   64

__device__ __forceinline__ float4 lerp4(float4 a, float4 b, float w) {
    float4 r;
    r.x = fmaf(w, b.x - a.x, a.x);
    r.y = fmaf(w, b.y - a.y, a.y);
    r.z = fmaf(w, b.z - a.z, a.z);
    r.w = fmaf(w, b.w - a.w, a.w);
    return r;
}

__global__ __launch_bounds__(256) void roi_pool_kernel(
    const float* __restrict__ fm, const int* __restrict__ rois,
    float* __restrict__ out, int n_rois)
{
    const int n = blockIdx.x;
    if (n >= n_rois) return;

    const int rx1 = rois[n * 4 + 0];
    const int ry1 = rois[n * 4 + 1];
    const int rx2 = rois[n * 4 + 2];
    const int ry2 = rois[n * 4 + 3];

    const int tid  = threadIdx.x;
    const int posg = tid >> 5;        // 0..7: which (py,px) position in this wave-slice
    const int lane = tid & 31;        // 0..31: channel group
    const int c    = lane << 2;       // channel offset (float4)

    float4* outv = (float4*)(out + (size_t)n * (POOL * POOL * CH));

    if ((rx1 | ry1 | rx2 | ry2) == 0) {
        // reference: all-zero roi -> zero output
        float4 z = make_float4(0.f, 0.f, 0.f, 0.f);
        for (int pos = posg; pos < POOL * POOL; pos += 8)
            outv[pos * 32 + lane] = z;
        return;
    }

    const int hh = max(ry2 - ry1, 1);
    const int ww = max(rx2 - rx1, 1);
    const float hf = (float)hh;
    const float wf = (float)ww;

    for (int pos = posg; pos < POOL * POOL; pos += 8) {
        const int py = pos / POOL;
        const int px = pos - py * POOL;

        float yc = ((float)py + 0.5f) * hf / 7.0f - 0.5f;
        yc = fminf(fmaxf(yc, 0.0f), hf - 1.0f);
        float xc = ((float)px + 0.5f) * wf / 7.0f - 0.5f;
        xc = fminf(fmaxf(xc, 0.0f), wf - 1.0f);

        const int y0 = (int)floorf(yc);
        const int x0 = (int)floorf(xc);
        const int y1 = min(y0 + 1, hh - 1);
        const int x1 = min(x0 + 1, ww - 1);
        const float wy = yc - (float)y0;
        const float wx = xc - (float)x0;

        const int ya0 = y0 + ry1, ya1 = y1 + ry1;
        const int xa0 = x0 + rx1, xa1 = x1 + rx1;

        const float4 g00 = *(const float4*)(fm + ((size_t)ya0 * FW + xa0) * CH + c);
        const float4 g01 = *(const float4*)(fm + ((size_t)ya0 * FW + xa1) * CH + c);
        const float4 g10 = *(const float4*)(fm + ((size_t)ya1 * FW + xa0) * CH + c);
        const float4 g11 = *(const float4*)(fm + ((size_t)ya1 * FW + xa1) * CH + c);

        const float4 top = lerp4(g00, g01, wx);
        const float4 bot = lerp4(g10, g11, wx);
        const float4 res = lerp4(top, bot, wy);

        outv[pos * 32 + lane] = res;
    }
}

extern "C" void kernel_launch(void* const* d_in, const int* in_sizes, int n_in,
                              void* d_out, int out_size, void* d_ws, size_t ws_size,
                              hipStream_t stream) {
    const float* fm   = (const float*)d_in[0];
    const int*   rois = (const int*)d_in[1];
    float*       out  = (float*)d_out;
    const int n_rois  = in_sizes[1] / 4;  // (1, N, 4) int32

    roi_pool_kernel<<<n_rois, 256, 0, stream>>>(fm, rois, out, n_rois);
}